// Round 7
// baseline (543.980 us; speedup 1.0000x reference)
//
#include <hip/hip_runtime.h>
#include <math.h>

#define O_  32
#define I_  32
#define K_  13
#define N_  4096
#define IK  (I_ * K_)     // 416
#define OIK (O_ * IK)     // 13312
#define NB  4             // n's per block
#define REPG 40           // DIAGNOSTIC: repeat gather+W phase 40x so the
                          // kernel dispatch tops the 131us fills and its
                          // duration reveals per-rep gather cost G_w.

typedef float f32x4 __attribute__((ext_vector_type(4)));

// Round 7 (instrumented): EXACT R1 structure (best known, 291.5us), with the
// gather+W phase repeated REPG times. Pointers laundered per rep via empty
// asm (memory clobber) so the compiler cannot CSE the repeats. Each rep
// rewrites identical values -> idempotent -> passes correctness.
// Reads: dispatch dur ~= 50 + 39*G_w; VALUBusy/Occupancy/FETCH of the real
// kernel become visible for the first time.
__global__ __launch_bounds__(256, 4) void plaq_kernel(
    const float* __restrict__ x,      // (I, N)
    const float* __restrict__ W,      // (O, I, K)
    const float* __restrict__ b,      // (O,)
    const float* __restrict__ mask,   // (N, O, I, K)
    const int*   __restrict__ shifts, // (N, K)
    float* __restrict__ out)          // (O, N)
{
    __shared__ __align__(16) float g_lds[NB][IK];
    const int n0  = blockIdx.x * NB;
    const int tid = threadIdx.x;
    const int o   = tid >> 3;
    const int s8  = tid & 7;

    const float* xp = x;
    const int*   sp = shifts;
    const float* wp = W;

    f32x4 w[13];

#pragma unroll 1
    for (int rg = 0; rg < REPG; ++rg) {
        // Launder pointers: blocks CSE across reps without adding real work.
        asm volatile("" : "+r"(xp), "+r"(sp), "+r"(wp) :: "memory");

        // Gather g[nl][i*13+k] = x[i*N + shifts[(n0+nl)*13+k]]  (1664 elems).
        for (int idx = tid; idx < NB * IK; idx += 256) {
            int nl = idx / IK;
            int r  = idx - nl * IK;
            int i  = r / K_;
            int k  = r - i * K_;
            int s  = sp[(n0 + nl) * K_ + k];
            g_lds[nl][r] = xp[i * N_ + s];
        }

        // W into registers (same values each rep).
        const f32x4* w4 = (const f32x4*)(wp + o * IK);
#pragma unroll
        for (int m = 0; m < 13; ++m) w[m] = w4[s8 + 8 * m];
    }

    const float bo = b[o];

    __syncthreads();

    const float scale = (float)((2.0 + 2.0 * M_E) / (M_E - 1.0));

    for (int nl = 0; nl < NB; ++nl) {
        const int n = n0 + nl;
        const f32x4* m4 = (const f32x4*)(mask + (size_t)n * OIK + o * IK);
        const f32x4* g4 = (const f32x4*)(&g_lds[nl][0]);

        float a0 = 0.f, a1 = 0.f, a2 = 0.f, a3 = 0.f;
#pragma unroll
        for (int m = 0; m < 13; ++m) {
            f32x4 mv = m4[s8 + 8 * m];      // plain load (R4: == nt, cold)
            f32x4 wg = w[m] * g4[s8 + 8 * m];
            a0 = fmaf(mv.x, wg.x, a0);
            a1 = fmaf(mv.y, wg.y, a1);
            a2 = fmaf(mv.z, wg.z, a2);
            a3 = fmaf(mv.w, wg.w, a3);
        }
        float acc = (a0 + a1) + (a2 + a3);

        // Reduce across the 8 lanes sharing this o (within one wave).
        acc += __shfl_down(acc, 4);
        acc += __shfl_down(acc, 2);
        acc += __shfl_down(acc, 1);

        if (s8 == 0) {
            float y  = acc + bo;
            float sg = 1.0f / (1.0f + __expf(-y));
            out[o * N_ + n] = (sg - 0.5f) * scale;
        }
    }
}

extern "C" void kernel_launch(void* const* d_in, const int* in_sizes, int n_in,
                              void* d_out, int out_size, void* d_ws, size_t ws_size,
                              hipStream_t stream) {
    const float* x      = (const float*)d_in[0];
    const float* Wconv  = (const float*)d_in[1];
    const float* bconv  = (const float*)d_in[2];
    const float* mask   = (const float*)d_in[3];
    const int*   shifts = (const int*)d_in[4];
    float* out = (float*)d_out;

    plaq_kernel<<<N_ / NB, 256, 0, stream>>>(x, Wconv, bconv, mask, shifts, out);
}

// Round 8
// 304.418 us; speedup vs baseline: 1.7870x; 1.7870x over previous
//
#include <hip/hip_runtime.h>
#include <math.h>

#define O_  32
#define I_  32
#define K_  13
#define N_  4096
#define IK  (I_ * K_)     // 416
#define OIK (O_ * IK)     // 13312
#define NT  4             // n's per block (grid-strided)
#define GRID 1024

typedef float f32x4 __attribute__((ext_vector_type(4)));

// Round 8: grid-strided n + double-buffered gather.
// Counter-derived model (R7): floor=208us, cold kernel=84us of which the
// mask stream is ~77us vs ~20us ideal (1.5-3 TB/s effective, while the SAME
// loop hits 35 TB/s L3-warm in R4). Theory: 1024 concurrent disjoint block
// streams destroy DRAM page locality; the harness fills hit 6.7 TB/s with a
// grid-strided single moving front. So: block b handles n = b + t*1024 --
// all resident blocks read inside one contiguous ~53MB window sweeping the
// mask. Gather for n+1024 is double-buffered in LDS and overlaps the stream
// of n (hides 3 of 4 gathers). Inner loop/lane map/FMA order identical to
// R1 -> bitwise-identical output.
__global__ __launch_bounds__(256, 4) void plaq_kernel(
    const float* __restrict__ x,      // (I, N)
    const float* __restrict__ W,      // (O, I, K)
    const float* __restrict__ b,      // (O,)
    const float* __restrict__ mask,   // (N, O, I, K)
    const int*   __restrict__ shifts, // (N, K)
    float* __restrict__ out)          // (O, N)
{
    __shared__ __align__(16) float g_lds[2][IK];
    const int tid = threadIdx.x;
    const int o   = tid >> 3;
    const int s8  = tid & 7;

    // 2-level, 2-slot clamped gather of n's g-row into LDS buffer bf.
    auto gather = [&](int n, int bf) {
        const int idx0 = tid;                 // < 416 always (256 threads)
        const int idx1 = tid + 256;
        const int v1   = (idx1 < IK);
        const int i0 = idx0 / K_, k0 = idx0 - i0 * K_;
        const int j1 = v1 ? idx1 : 0;
        const int i1 = j1 / K_,  k1 = j1 - i1 * K_;
        const int s0 = shifts[n * K_ + k0];   // level 1: independent
        const int s1 = shifts[n * K_ + k1];
        const float x0 = x[i0 * N_ + s0];     // level 2: independent
        const float x1 = x[i1 * N_ + s1];
        g_lds[bf][idx0] = x0;
        if (v1) g_lds[bf][idx1] = x1;
    };

    // First gather + W hoist (independent, in flight together).
    gather(blockIdx.x, 0);

    const f32x4* w4 = (const f32x4*)(W + o * IK);
    f32x4 w[13];
#pragma unroll
    for (int m = 0; m < 13; ++m) w[m] = w4[s8 + 8 * m];
    const float bo = b[o];

    __syncthreads();

    const float scale = (float)((2.0 + 2.0 * M_E) / (M_E - 1.0));

#pragma unroll
    for (int t = 0; t < NT; ++t) {
        const int n  = blockIdx.x + t * GRID;
        const int cur = t & 1;

        // Prefetch next n's gather into the other buffer; its global loads
        // overlap this n's mask stream (no dependency until next barrier).
        if (t + 1 < NT) gather(n + GRID, cur ^ 1);

        const f32x4* m4 = (const f32x4*)(mask + (size_t)n * OIK + o * IK);
        const f32x4* g4 = (const f32x4*)(&g_lds[cur][0]);

        float a0 = 0.f, a1 = 0.f, a2 = 0.f, a3 = 0.f;
#pragma unroll
        for (int m = 0; m < 13; ++m) {
            f32x4 mv = m4[s8 + 8 * m];        // plain load: allow L3
            f32x4 wg = w[m] * g4[s8 + 8 * m];
            a0 = fmaf(mv.x, wg.x, a0);
            a1 = fmaf(mv.y, wg.y, a1);
            a2 = fmaf(mv.z, wg.z, a2);
            a3 = fmaf(mv.w, wg.w, a3);
        }
        float acc = (a0 + a1) + (a2 + a3);

        // Reduce across the 8 lanes sharing this o (within one wave).
        acc += __shfl_down(acc, 4);
        acc += __shfl_down(acc, 2);
        acc += __shfl_down(acc, 1);

        if (s8 == 0) {
            float y  = acc + bo;
            float sg = 1.0f / (1.0f + __expf(-y));
            out[o * N_ + n] = (sg - 0.5f) * scale;
        }

        __syncthreads();   // next buffer's gather complete; cur reads done
    }
}

extern "C" void kernel_launch(void* const* d_in, const int* in_sizes, int n_in,
                              void* d_out, int out_size, void* d_ws, size_t ws_size,
                              hipStream_t stream) {
    const float* x      = (const float*)d_in[0];
    const float* Wconv  = (const float*)d_in[1];
    const float* bconv  = (const float*)d_in[2];
    const float* mask   = (const float*)d_in[3];
    const int*   shifts = (const int*)d_in[4];
    float* out = (float*)d_out;

    plaq_kernel<<<GRID, 256, 0, stream>>>(x, Wconv, bconv, mask, shifts, out);
}